// Round 9
// baseline (284.893 us; speedup 1.0000x reference)
//
#include <hip/hip_runtime.h>
#include <hip/hip_bf16.h>

#define B_ 32
#define T_ 40
#define P_ 256
#define V_ 4096
#define D_ 256
#define DINO_ 384
#define H_ 4
#define L_ 2
#define HD_ 64
#define DFF_ 1024
#define EPS_ 1e-5f

typedef __bf16 bf16;
typedef __bf16 bf16x8 __attribute__((ext_vector_type(8)));
typedef float f32x4 __attribute__((ext_vector_type(4)));

// bf16 weight arena offsets (elements)
#define OFF_QKV 0            // 2 x 768*256
#define OFF_OUTW 393216      // 2 x 256*256
#define OFF_W1 524288        // 2 x 1024*256
#define OFF_W2 1048576       // 2 x 256*1024
#define OFF_FUS 1572864      // 256*640
#define WB_TOTAL 1736704
#define CONV_BLOCKS 848      // WB_TOTAL / 2048
#define PAT_BLOCKS 1536      // 32*256*384 / 2048

__device__ __forceinline__ bf16x8 cvt8(const float* p) {
  float4 f0 = *(const float4*)p;
  float4 f1 = *(const float4*)(p + 4);
  bf16x8 v;
  v[0] = (bf16)f0.x; v[1] = (bf16)f0.y; v[2] = (bf16)f0.z; v[3] = (bf16)f0.w;
  v[4] = (bf16)f1.x; v[5] = (bf16)f1.y; v[6] = (bf16)f1.z; v[7] = (bf16)f1.w;
  return v;
}

// ---- prep: embed | fus_w2 transpose->bf16 | weights->bf16 | patches->bf16 --
__global__ __launch_bounds__(256) void prep_k(
    const int* __restrict__ tokens, const float* __restrict__ tok_emb,
    const float* __restrict__ pos_emb, float* __restrict__ x,
    const float* __restrict__ fus_w2, bf16* __restrict__ w2Tb,
    const float* __restrict__ qkv_w, const float* __restrict__ out_w,
    const float* __restrict__ w1, const float* __restrict__ w2,
    const float* __restrict__ fus_w1, bf16* __restrict__ wb,
    const float* __restrict__ patches, bf16* __restrict__ patb) {
  __shared__ float tile[32][33];
  int bi = blockIdx.x;
  int tid = threadIdx.x;
  if (bi < B_ * T_) {
    int t = bi % T_;
    x[bi * D_ + tid] = tok_emb[tokens[bi] * D_ + tid] + pos_emb[t * D_ + tid];
  } else if (bi < B_ * T_ + 64) {
    int tt = bi - B_ * T_;
    int bx = (tt & 7) * 32, by = (tt >> 3) * 32;
    int tx = tid & 31, ty = tid >> 5;  // 32 x 8
#pragma unroll
    for (int i = 0; i < 32; i += 8) tile[ty + i][tx] = fus_w2[(by + ty + i) * D_ + bx + tx];
    __syncthreads();
#pragma unroll
    for (int i = 0; i < 32; i += 8)
      w2Tb[(bx + ty + i) * D_ + by + tx] = (bf16)tile[tx][ty + i];
  } else if (bi < B_ * T_ + 64 + CONV_BLOCKS) {
    long f = (long)(bi - B_ * T_ - 64) * 2048 + tid * 8;
    const float* src;
    long off;
    if (f < OFF_OUTW)      { src = qkv_w;  off = f - OFF_QKV; }
    else if (f < OFF_W1)   { src = out_w;  off = f - OFF_OUTW; }
    else if (f < OFF_W2)   { src = w1;     off = f - OFF_W1; }
    else if (f < OFF_FUS)  { src = w2;     off = f - OFF_W2; }
    else                   { src = fus_w1; off = f - OFF_FUS; }
    *(bf16x8*)&wb[f] = cvt8(src + off);
  } else {
    long f = (long)(bi - B_ * T_ - 64 - CONV_BLOCKS) * 2048 + tid * 8;
    *(bf16x8*)&patb[f] = cvt8(patches + f);
  }
}

// ---- 64x64 MFMA GEMM: 4 waves, each 64m x 16n; W bf16 --------------------
// C[m,n] = act(A @ W^T + bias). Grid (N/64, M/64).
template <int ABF16, int OBF16, int RELU>
__global__ __launch_bounds__(256) void gemm64_k(
    const void* __restrict__ Av, const bf16* __restrict__ W,
    const float* __restrict__ bias, void* __restrict__ outv,
    int K, int lda, int ldw, int ldc) {
  __shared__ bf16 As[64 * 72];
  __shared__ bf16 Ws[64 * 72];
  const int tid = threadIdx.x;
  const int lane = tid & 63;
  const int wv = tid >> 6;
  const int col = lane & 15, quad = lane >> 4;
  const int bn = blockIdx.x * 64, bm = blockIdx.y * 64;
  const float* Af = (const float*)Av;
  const bf16* Ab = (const bf16*)Av;

  f32x4 acc[4];
#pragma unroll
  for (int i = 0; i < 4; ++i) acc[i] = (f32x4){0.f, 0.f, 0.f, 0.f};

  for (int kk = 0; kk < K; kk += 64) {
#pragma unroll
    for (int it = 0; it < 2; ++it) {
      int c = tid + it * 256;
      int row = c >> 3, kc = (c & 7) * 8;
      if (ABF16)
        *(bf16x8*)&As[row * 72 + kc] = *(const bf16x8*)(Ab + (long)(bm + row) * lda + kk + kc);
      else
        *(bf16x8*)&As[row * 72 + kc] = cvt8(Af + (long)(bm + row) * lda + kk + kc);
      *(bf16x8*)&Ws[row * 72 + kc] = *(const bf16x8*)(W + (long)(bn + row) * ldw + kk + kc);
    }
    __syncthreads();
#pragma unroll
    for (int ki = 0; ki < 2; ++ki) {
      bf16x8 bfr = *(const bf16x8*)&Ws[(wv * 16 + col) * 72 + ki * 32 + quad * 8];
#pragma unroll
      for (int i = 0; i < 4; ++i) {
        bf16x8 afr = *(const bf16x8*)&As[(i * 16 + col) * 72 + ki * 32 + quad * 8];
        acc[i] = __builtin_amdgcn_mfma_f32_16x16x32_bf16(afr, bfr, acc[i], 0, 0, 0);
      }
    }
    __syncthreads();
  }
  const int n = bn + wv * 16 + col;
  float bv = bias ? bias[n] : 0.0f;
#pragma unroll
  for (int i = 0; i < 4; ++i) {
#pragma unroll
    for (int r = 0; r < 4; ++r) {
      int m = bm + i * 16 + quad * 4 + r;
      float val = acc[i][r] + bv;
      if (RELU) val = fmaxf(val, 0.0f);
      if (OBF16) ((bf16*)outv)[(long)m * ldc + n] = (bf16)val;
      else ((float*)outv)[(long)m * ldc + n] = val;
    }
  }
}

// ---- full-row GEMM + bias + resid + LayerNorm epilogue --------------------
// Tile 32m x 256n (whole N). Grid (M/32). Wave wv owns n in [wv*64, wv*64+64).
// xout = LN(A@W^T + bias + resid) rows.
template <int ABF16>
__global__ __launch_bounds__(256) void gemmln_k(
    const void* __restrict__ Av, const bf16* __restrict__ W,
    const float* __restrict__ bias, const float* __restrict__ resid,
    const float* __restrict__ lng, const float* __restrict__ lnb,
    float* __restrict__ xout, int K) {
  __shared__ bf16 As[32 * 72];
  __shared__ bf16 Ws[256 * 72];
  __shared__ float2 wred[4][32];
  const int tid = threadIdx.x;
  const int lane = tid & 63;
  const int wv = tid >> 6;
  const int col = lane & 15, quad = lane >> 4;
  const int bm = blockIdx.x * 32;
  const int srow = tid >> 3, kc = (tid & 7) * 8;
  const float* Af = (const float*)Av;
  const bf16* Ab = (const bf16*)Av;

  f32x4 acc[2][4];
#pragma unroll
  for (int mt = 0; mt < 2; ++mt)
#pragma unroll
    for (int nt = 0; nt < 4; ++nt) acc[mt][nt] = (f32x4){0.f, 0.f, 0.f, 0.f};

  for (int kk = 0; kk < K; kk += 64) {
    if (ABF16)
      *(bf16x8*)&As[srow * 72 + kc] = *(const bf16x8*)(Ab + (long)(bm + srow) * K + kk + kc);
    else
      *(bf16x8*)&As[srow * 72 + kc] = cvt8(Af + (long)(bm + srow) * K + kk + kc);
#pragma unroll
    for (int i = 0; i < 8; ++i) {
      int c = tid + i * 256;
      int r = c >> 3, k2 = (c & 7) * 8;
      *(bf16x8*)&Ws[r * 72 + k2] = *(const bf16x8*)(W + (long)r * K + kk + k2);
    }
    __syncthreads();
#pragma unroll
    for (int ki = 0; ki < 2; ++ki) {
#pragma unroll
      for (int nt = 0; nt < 4; ++nt) {
        bf16x8 bfr = *(const bf16x8*)&Ws[(wv * 64 + nt * 16 + col) * 72 + ki * 32 + quad * 8];
#pragma unroll
        for (int mt = 0; mt < 2; ++mt) {
          bf16x8 afr = *(const bf16x8*)&As[(mt * 16 + col) * 72 + ki * 32 + quad * 8];
          acc[mt][nt] = __builtin_amdgcn_mfma_f32_16x16x32_bf16(afr, bfr, acc[mt][nt], 0, 0, 0);
        }
      }
    }
    __syncthreads();
  }

  // epilogue: bias + resid, then LN over each full 256-wide row
  float biasv[4], gv[4], bvv[4];
#pragma unroll
  for (int nt = 0; nt < 4; ++nt) {
    int n = wv * 64 + nt * 16 + col;
    biasv[nt] = bias[n];
    gv[nt] = lng[n];
    bvv[nt] = lnb[n];
  }
  float rsum[2][4], rss[2][4];
#pragma unroll
  for (int mt = 0; mt < 2; ++mt)
#pragma unroll
    for (int r = 0; r < 4; ++r) {
      int m = bm + mt * 16 + quad * 4 + r;
      float s = 0.f, q = 0.f;
#pragma unroll
      for (int nt = 0; nt < 4; ++nt) {
        int n = wv * 64 + nt * 16 + col;
        float v = acc[mt][nt][r] + biasv[nt] + resid[(long)m * D_ + n];
        acc[mt][nt][r] = v;
        s += v;
        q += v * v;
      }
      rsum[mt][r] = s;
      rss[mt][r] = q;
    }
#pragma unroll
  for (int mk = 1; mk < 16; mk <<= 1)
#pragma unroll
    for (int mt = 0; mt < 2; ++mt)
#pragma unroll
      for (int r = 0; r < 4; ++r) {
        rsum[mt][r] += __shfl_xor(rsum[mt][r], mk);
        rss[mt][r] += __shfl_xor(rss[mt][r], mk);
      }
  if (col == 0) {
#pragma unroll
    for (int mt = 0; mt < 2; ++mt)
#pragma unroll
      for (int r = 0; r < 4; ++r) {
        float2 p; p.x = rsum[mt][r]; p.y = rss[mt][r];
        wred[wv][mt * 16 + quad * 4 + r] = p;
      }
  }
  __syncthreads();
#pragma unroll
  for (int mt = 0; mt < 2; ++mt)
#pragma unroll
    for (int r = 0; r < 4; ++r) {
      int ml = mt * 16 + quad * 4 + r;
      float s = 0.f, q = 0.f;
#pragma unroll
      for (int w = 0; w < 4; ++w) {
        float2 p = wred[w][ml];
        s += p.x;
        q += p.y;
      }
      float mean = s * (1.0f / D_);
      float inv = rsqrtf(q * (1.0f / D_) - mean * mean + EPS_);
#pragma unroll
      for (int nt = 0; nt < 4; ++nt) {
        int n = wv * 64 + nt * 16 + col;
        xout[(long)(bm + ml) * D_ + n] =
            (acc[mt][nt][r] - mean) * inv * gv[nt] + bvv[nt];
      }
    }
}

// ---- causal attention, (h, b, q-half) per block ----------------------------
__global__ __launch_bounds__(256) void attn_k(const float* __restrict__ qkv,
                                              float* __restrict__ ctx) {
  __shared__ float q[20][HD_ + 1];
  __shared__ float k[T_][HD_ + 1];
  __shared__ float v[T_][HD_ + 1];
  __shared__ float s[20][T_ + 1];
  int h = blockIdx.x, b = blockIdx.y, zq = blockIdx.z;
  int r0 = zq * 20;
  int tid = threadIdx.x;
  for (int idx = tid; idx < T_ * HD_; idx += 256) {
    int t = idx >> 6, d = idx & 63;
    long base = (long)(b * T_ + t) * (3 * D_) + h * HD_ + d;
    k[t][d] = qkv[base + D_];
    v[t][d] = qkv[base + 2 * D_];
    if (t < 20) q[t][d] = qkv[(long)(b * T_ + r0 + t) * (3 * D_) + h * HD_ + d];
  }
  __syncthreads();
  for (int idx = tid; idx < 20 * T_; idx += 256) {
    int i = idx / T_, j = idx - i * T_;
    if (j <= r0 + i) {
      float acc = 0.f;
#pragma unroll
      for (int d = 0; d < HD_; ++d) acc += q[i][d] * k[j][d];
      s[i][j] = acc * 0.125f;
    }
  }
  __syncthreads();
  if (tid < 20) {
    int i = tid, hi = r0 + i;
    float mx = -1e30f;
    for (int j = 0; j <= hi; ++j) mx = fmaxf(mx, s[i][j]);
    float sum = 0.f;
    for (int j = 0; j <= hi; ++j) {
      float e = __expf(s[i][j] - mx);
      s[i][j] = e;
      sum += e;
    }
    float inv = 1.0f / sum;
    for (int j = 0; j <= hi; ++j) s[i][j] *= inv;
  }
  __syncthreads();
  for (int idx = tid; idx < 20 * HD_; idx += 256) {
    int i = idx >> 6, d = idx & 63;
    int hi = r0 + i;
    float acc = 0.f;
    for (int j = 0; j <= hi; ++j) acc += s[i][j] * v[j][d];
    ctx[(long)(b * T_ + hi) * D_ + h * HD_ + d] = acc;
  }
}

// ---- fused pproj/cproj/weff, 64x64 tiles; grid (4, 128+20+20) -------------
__global__ __launch_bounds__(256) void fuse3_k(
    const bf16* __restrict__ patb, const float* __restrict__ xbuf,
    const float* __restrict__ cls_w, const bf16* __restrict__ fusb,
    const bf16* __restrict__ w2Tb, const float* __restrict__ fus_b1,
    const int* __restrict__ tokens, float* __restrict__ pprojT,
    float* __restrict__ cw) {
  __shared__ bf16 As[64 * 72];
  __shared__ bf16 Ws[64 * 72];
  const int tid = threadIdx.x;
  const int lane = tid & 63;
  const int wv = tid >> 6;
  const int col = lane & 15, quad = lane >> 4;
  const int bn = blockIdx.x * 64;
  const int y = blockIdx.y;
  int job, bm;
  if (y < 128) { job = 0; bm = y * 64; }
  else if (y < 148) { job = 1; bm = (y - 128) * 64; }
  else { job = 2; bm = (y - 148) * 64; }
  const int K = (job == 0) ? DINO_ : D_;

  f32x4 acc[4];
#pragma unroll
  for (int i = 0; i < 4; ++i) acc[i] = (f32x4){0.f, 0.f, 0.f, 0.f};
  bf16x8 z8 = {};

  for (int kk = 0; kk < K; kk += 64) {
#pragma unroll
    for (int it = 0; it < 2; ++it) {
      int c = tid + it * 256;
      int row = c >> 3, kc = (c & 7) * 8;
      int gm = bm + row;
      bf16x8 av;
      const bf16* wp;
      if (job == 0) {
        av = *(const bf16x8*)(patb + (long)gm * DINO_ + kk + kc);
        wp = fusb + (long)(bn + row) * 640 + kk + kc;
      } else if (job == 1) {
        int t = gm % T_;
        av = (t == 0) ? z8 : cvt8(xbuf + (long)(gm - 1) * D_ + kk + kc);
        wp = fusb + 384 + (long)(bn + row) * 640 + kk + kc;
      } else {
        av = cvt8(cls_w + (long)tokens[gm] * D_ + kk + kc);
        wp = w2Tb + (long)(bn + row) * D_ + kk + kc;
      }
      *(bf16x8*)&As[row * 72 + kc] = av;
      *(bf16x8*)&Ws[row * 72 + kc] = *(const bf16x8*)wp;
    }
    __syncthreads();
#pragma unroll
    for (int ki = 0; ki < 2; ++ki) {
      bf16x8 bfr = *(const bf16x8*)&Ws[(wv * 16 + col) * 72 + ki * 32 + quad * 8];
#pragma unroll
      for (int i = 0; i < 4; ++i) {
        bf16x8 afr = *(const bf16x8*)&As[(i * 16 + col) * 72 + ki * 32 + quad * 8];
        acc[i] = __builtin_amdgcn_mfma_f32_16x16x32_bf16(afr, bfr, acc[i], 0, 0, 0);
      }
    }
    __syncthreads();
  }
  const int n = bn + wv * 16 + col;
  if (job == 0) {
#pragma unroll
    for (int i = 0; i < 4; ++i)
#pragma unroll
      for (int r = 0; r < 4; ++r) {
        int m = bm + i * 16 + quad * 4 + r;
        int b = m >> 8, p = m & 255;
        pprojT[(long)b * (D_ * P_) + (long)n * P_ + p] = acc[i][r];
      }
  } else if (job == 1) {
    float bv = fus_b1[n];
#pragma unroll
    for (int i = 0; i < 4; ++i)
#pragma unroll
      for (int r = 0; r < 4; ++r) {
        int m = bm + i * 16 + quad * 4 + r;
        cw[(long)m * (2 * D_) + n * 2] = acc[i][r] + bv;
      }
  } else {
#pragma unroll
    for (int i = 0; i < 4; ++i)
#pragma unroll
      for (int r = 0; r < 4; ++r) {
        int m = bm + i * 16 + quad * 4 + r;
        cw[(long)m * (2 * D_) + n * 2 + 1] = acc[i][r];
      }
  }
}

// ---- final: out[b,p,t] = sigmoid(sum_e gelu(pp+cp)*we + beff) -------------
__global__ __launch_bounds__(256) void final_k(const float* __restrict__ pprojT,
                                               const float* __restrict__ cw,
                                               const int* __restrict__ tokens,
                                               const float* __restrict__ cls_w,
                                               const float* __restrict__ cls_b,
                                               const float* __restrict__ fus_b2,
                                               float* __restrict__ out) {
  __shared__ float2 cws[4][D_];
  int tid = threadIdx.x;
  int lane = tid & 63, wv = tid >> 6;
  int p = blockIdx.x * 64 + lane;
  int t = blockIdx.y * 4 + wv;
  int b = blockIdx.z;
  int mbase = b * T_ + blockIdx.y * 4;
  for (int idx = tid; idx < 4 * D_; idx += 256) {
    int tt = idx >> 8, e = idx & 255;
    cws[tt][e] = ((const float2*)cw)[(long)(mbase + tt) * D_ + e];
  }
  __syncthreads();

  int m = b * T_ + t;
  int tok = tokens[m];
  const float* cr = cls_w + (long)tok * D_;
  float bacc = 0.f;
#pragma unroll
  for (int i = 0; i < 4; ++i) bacc += cr[lane + i * 64] * fus_b2[lane + i * 64];
#pragma unroll
  for (int mk = 1; mk < 64; mk <<= 1) bacc += __shfl_xor(bacc, mk);
  float beff = bacc + cls_b[tok];

  const float* ppb = pprojT + (long)b * (D_ * P_);  // [e][p]
  float acc = 0.f;
#pragma unroll 8
  for (int e = 0; e < D_; ++e) {
    float pp = ppb[e * P_ + p];
    float2 c = cws[wv][e];
    float x = pp + c.x;
    float x2 = x * x;
    float u = x * fmaf(-0.1029432f, x2, -2.3022083f);  // -log2e*1.5958*(x+0.044715x^3)
    float ex = __builtin_amdgcn_exp2f(u);
    float r = __builtin_amdgcn_rcpf(1.0f + ex);
    acc = fmaf(x * r, c.y, acc);
  }
  float logit = acc + beff;
  float es = __builtin_amdgcn_exp2f(-1.4426950408889634f * logit);
  out[(long)(b * P_ + p) * T_ + t] = __builtin_amdgcn_rcpf(1.0f + es);
}

extern "C" void kernel_launch(void* const* d_in, const int* in_sizes, int n_in, void* d_out,
                              int out_size, void* d_ws, size_t ws_size, hipStream_t stream) {
  const float* patches = (const float*)d_in[0];
  const int* tokens = (const int*)d_in[1];
  const float* tok_emb = (const float*)d_in[2];
  const float* pos_emb = (const float*)d_in[3];
  const float* qkv_w = (const float*)d_in[4];
  const float* qkv_b = (const float*)d_in[5];
  const float* out_w = (const float*)d_in[6];
  const float* out_b = (const float*)d_in[7];
  const float* ln1_s = (const float*)d_in[8];
  const float* ln1_b = (const float*)d_in[9];
  const float* w1 = (const float*)d_in[10];
  const float* b1 = (const float*)d_in[11];
  const float* w2 = (const float*)d_in[12];
  const float* b2 = (const float*)d_in[13];
  const float* ln2_s = (const float*)d_in[14];
  const float* ln2_b = (const float*)d_in[15];
  const float* fus_w1 = (const float*)d_in[16];
  const float* fus_b1 = (const float*)d_in[17];
  const float* fus_w2 = (const float*)d_in[18];
  const float* fus_b2 = (const float*)d_in[19];
  const float* cls_w = (const float*)d_in[20];
  const float* cls_b = (const float*)d_in[21];
  float* out = (float*)d_out;

  const int MT = B_ * T_;  // 1280
  float* x = (float*)d_ws;                     // 1280*256 (embed / LN outs)
  float* qkvbuf = x + MT * D_;                 // 1280*768
  float* attbuf = qkvbuf + MT * 3 * D_;        // 1280*256
  float* pprojT = attbuf + MT * D_;            // 32*256*256 [b][e][p]
  float* cwbuf = pprojT + (long)B_ * D_ * P_;  // 1280*512 {cproj,weff}
  bf16* wb = (bf16*)(cwbuf + MT * D_ * 2);     // bf16 weight arena
  bf16* w2Tb = wb + WB_TOTAL;                  // 256*256
  bf16* patb = w2Tb + D_ * D_;                 // 32*256*384
  bf16* hb = patb + (long)B_ * P_ * DINO_;     // 1280*1024 bf16

  prep_k<<<MT + 64 + CONV_BLOCKS + PAT_BLOCKS, 256, 0, stream>>>(
      tokens, tok_emb, pos_emb, x, fus_w2, w2Tb, qkv_w, out_w, w1, w2, fus_w1, wb,
      patches, patb);

  for (int l = 0; l < L_; ++l) {
    // qkv = x @ qkv_w^T + qkv_b
    gemm64_k<0, 0, 0><<<dim3(12, 20), 256, 0, stream>>>(
        x, wb + OFF_QKV + (long)l * 3 * D_ * D_, qkv_b + l * 3 * D_, qkvbuf,
        D_, D_, D_, 3 * D_);
    attn_k<<<dim3(H_, B_, 2), 256, 0, stream>>>(qkvbuf, attbuf);
    // x = LN1(att @ out_w^T + out_b + x)
    gemmln_k<0><<<40, 256, 0, stream>>>(
        attbuf, wb + OFF_OUTW + (long)l * D_ * D_, out_b + l * D_, x,
        ln1_s + l * D_, ln1_b + l * D_, x, D_);
    // hb = relu(x @ w1^T + b1)  (bf16 out)
    gemm64_k<0, 1, 1><<<dim3(16, 20), 256, 0, stream>>>(
        x, wb + OFF_W1 + (long)l * DFF_ * D_, b1 + l * DFF_, hb, D_, D_, D_, DFF_);
    // x = LN2(hb @ w2^T + b2 + x)
    gemmln_k<1><<<40, 256, 0, stream>>>(
        hb, wb + OFF_W2 + (long)l * D_ * DFF_, b2 + l * D_, x,
        ln2_s + l * D_, ln2_b + l * D_, x, DFF_);
  }

  fuse3_k<<<dim3(4, 168), 256, 0, stream>>>(patb, x, cls_w, wb + OFF_FUS, w2Tb,
                                            fus_b1, tokens, pprojT, cwbuf);

  final_k<<<dim3(4, 10, 32), 256, 0, stream>>>(pprojT, cwbuf, tokens, cls_w, cls_b,
                                               fus_b2, out);
}

// Round 10
// 270.172 us; speedup vs baseline: 1.0545x; 1.0545x over previous
//
#include <hip/hip_runtime.h>
#include <hip/hip_bf16.h>

#define B_ 32
#define T_ 40
#define P_ 256
#define V_ 4096
#define D_ 256
#define DINO_ 384
#define H_ 4
#define L_ 2
#define HD_ 64
#define DFF_ 1024
#define EPS_ 1e-5f

typedef __bf16 bf16;
typedef __bf16 bf16x8 __attribute__((ext_vector_type(8)));
typedef float f32x4 __attribute__((ext_vector_type(4)));

// bf16 weight arena offsets (elements)
#define OFF_QKV 0            // 2 x 768*256
#define OFF_OUTW 393216      // 2 x 256*256
#define OFF_W1 524288        // 2 x 1024*256
#define OFF_W2 1048576       // 2 x 256*1024
#define OFF_FUS 1572864      // 256*640
#define WB_TOTAL 1736704
#define CONV_BLOCKS 848      // WB_TOTAL / 2048
#define PAT_BLOCKS 1536      // 32*256*384 / 2048

__device__ __forceinline__ bf16x8 cvt8(const float* p) {
  float4 f0 = *(const float4*)p;
  float4 f1 = *(const float4*)(p + 4);
  bf16x8 v;
  v[0] = (bf16)f0.x; v[1] = (bf16)f0.y; v[2] = (bf16)f0.z; v[3] = (bf16)f0.w;
  v[4] = (bf16)f1.x; v[5] = (bf16)f1.y; v[6] = (bf16)f1.z; v[7] = (bf16)f1.w;
  return v;
}

// ---- prep: embed | fus_w2 transpose->bf16 | weights->bf16 | patches->bf16 --
__global__ __launch_bounds__(256) void prep_k(
    const int* __restrict__ tokens, const float* __restrict__ tok_emb,
    const float* __restrict__ pos_emb, float* __restrict__ x,
    const float* __restrict__ fus_w2, bf16* __restrict__ w2Tb,
    const float* __restrict__ qkv_w, const float* __restrict__ out_w,
    const float* __restrict__ w1, const float* __restrict__ w2,
    const float* __restrict__ fus_w1, bf16* __restrict__ wb,
    const float* __restrict__ patches, bf16* __restrict__ patb) {
  __shared__ float tile[32][33];
  int bi = blockIdx.x;
  int tid = threadIdx.x;
  if (bi < B_ * T_) {
    int t = bi % T_;
    x[bi * D_ + tid] = tok_emb[tokens[bi] * D_ + tid] + pos_emb[t * D_ + tid];
  } else if (bi < B_ * T_ + 64) {
    int tt = bi - B_ * T_;
    int bx = (tt & 7) * 32, by = (tt >> 3) * 32;
    int tx = tid & 31, ty = tid >> 5;  // 32 x 8
#pragma unroll
    for (int i = 0; i < 32; i += 8) tile[ty + i][tx] = fus_w2[(by + ty + i) * D_ + bx + tx];
    __syncthreads();
#pragma unroll
    for (int i = 0; i < 32; i += 8)
      w2Tb[(bx + ty + i) * D_ + by + tx] = (bf16)tile[tx][ty + i];
  } else if (bi < B_ * T_ + 64 + CONV_BLOCKS) {
    long f = (long)(bi - B_ * T_ - 64) * 2048 + tid * 8;
    const float* src;
    long off;
    if (f < OFF_OUTW)      { src = qkv_w;  off = f - OFF_QKV; }
    else if (f < OFF_W1)   { src = out_w;  off = f - OFF_OUTW; }
    else if (f < OFF_W2)   { src = w1;     off = f - OFF_W1; }
    else if (f < OFF_FUS)  { src = w2;     off = f - OFF_W2; }
    else                   { src = fus_w1; off = f - OFF_FUS; }
    *(bf16x8*)&wb[f] = cvt8(src + off);
  } else {
    long f = (long)(bi - B_ * T_ - 64 - CONV_BLOCKS) * 2048 + tid * 8;
    *(bf16x8*)&patb[f] = cvt8(patches + f);
  }
}

// ---- 64x64 MFMA GEMM: 4 waves, each 64m x 16n; W bf16 --------------------
template <int ABF16, int OBF16, int RELU>
__global__ __launch_bounds__(256) void gemm64_k(
    const void* __restrict__ Av, const bf16* __restrict__ W,
    const float* __restrict__ bias, void* __restrict__ outv,
    int K, int lda, int ldw, int ldc) {
  __shared__ bf16 As[64 * 72];
  __shared__ bf16 Ws[64 * 72];
  const int tid = threadIdx.x;
  const int lane = tid & 63;
  const int wv = tid >> 6;
  const int col = lane & 15, quad = lane >> 4;
  const int bn = blockIdx.x * 64, bm = blockIdx.y * 64;
  const float* Af = (const float*)Av;
  const bf16* Ab = (const bf16*)Av;

  f32x4 acc[4];
#pragma unroll
  for (int i = 0; i < 4; ++i) acc[i] = (f32x4){0.f, 0.f, 0.f, 0.f};

  for (int kk = 0; kk < K; kk += 64) {
#pragma unroll
    for (int it = 0; it < 2; ++it) {
      int c = tid + it * 256;
      int row = c >> 3, kc = (c & 7) * 8;
      if (ABF16)
        *(bf16x8*)&As[row * 72 + kc] = *(const bf16x8*)(Ab + (long)(bm + row) * lda + kk + kc);
      else
        *(bf16x8*)&As[row * 72 + kc] = cvt8(Af + (long)(bm + row) * lda + kk + kc);
      *(bf16x8*)&Ws[row * 72 + kc] = *(const bf16x8*)(W + (long)(bn + row) * ldw + kk + kc);
    }
    __syncthreads();
#pragma unroll
    for (int ki = 0; ki < 2; ++ki) {
      bf16x8 bfr = *(const bf16x8*)&Ws[(wv * 16 + col) * 72 + ki * 32 + quad * 8];
#pragma unroll
      for (int i = 0; i < 4; ++i) {
        bf16x8 afr = *(const bf16x8*)&As[(i * 16 + col) * 72 + ki * 32 + quad * 8];
        acc[i] = __builtin_amdgcn_mfma_f32_16x16x32_bf16(afr, bfr, acc[i], 0, 0, 0);
      }
    }
    __syncthreads();
  }
  const int n = bn + wv * 16 + col;
  float bv = bias ? bias[n] : 0.0f;
#pragma unroll
  for (int i = 0; i < 4; ++i) {
#pragma unroll
    for (int r = 0; r < 4; ++r) {
      int m = bm + i * 16 + quad * 4 + r;
      float val = acc[i][r] + bv;
      if (RELU) val = fmaxf(val, 0.0f);
      if (OBF16) ((bf16*)outv)[(long)m * ldc + n] = (bf16)val;
      else ((float*)outv)[(long)m * ldc + n] = val;
    }
  }
}

// ---- 32x32 staged MFMA GEMM with optional residual epilogue ---------------
template <int ABF16, int RESID>
__global__ __launch_bounds__(256) void gemm_k(
    const void* __restrict__ Av, const bf16* __restrict__ W,
    const float* __restrict__ bias, const float* __restrict__ resid,
    float* __restrict__ outv, int K, int lda, int ldw, int ldc) {
  __shared__ bf16 As[32 * 72];
  __shared__ bf16 Ws[32 * 72];
  const int tid = threadIdx.x;
  const int lane = tid & 63;
  const int wv = tid >> 6;
  const int mi = wv & 1, ni = wv >> 1;
  const int col = lane & 15, quad = lane >> 4;
  const int bn = blockIdx.x * 32, bm = blockIdx.y * 32;
  const int srow = tid >> 3, kc = (tid & 7) * 8;
  const float* Af = (const float*)Av;
  const bf16* Ab = (const bf16*)Av;
  const bf16* Wp = W + (long)(bn + srow) * ldw + kc;

  f32x4 acc = {0.f, 0.f, 0.f, 0.f};
  for (int kk = 0; kk < K; kk += 64) {
    if (ABF16)
      *(bf16x8*)&As[srow * 72 + kc] = *(const bf16x8*)(Ab + (long)(bm + srow) * lda + kk + kc);
    else
      *(bf16x8*)&As[srow * 72 + kc] = cvt8(Af + (long)(bm + srow) * lda + kk + kc);
    *(bf16x8*)&Ws[srow * 72 + kc] = *(const bf16x8*)(Wp + kk);
    __syncthreads();
#pragma unroll
    for (int ki = 0; ki < 2; ++ki) {
      bf16x8 afr = *(const bf16x8*)&As[(mi * 16 + col) * 72 + ki * 32 + quad * 8];
      bf16x8 bfr = *(const bf16x8*)&Ws[(ni * 16 + col) * 72 + ki * 32 + quad * 8];
      acc = __builtin_amdgcn_mfma_f32_16x16x32_bf16(afr, bfr, acc, 0, 0, 0);
    }
    __syncthreads();
  }
  const int n = bn + ni * 16 + col;
  float bv = bias ? bias[n] : 0.0f;
#pragma unroll
  for (int r = 0; r < 4; ++r) {
    int m = bm + mi * 16 + quad * 4 + r;
    float val = acc[r] + bv;
    if (RESID) val += resid[(long)m * D_ + n];
    outv[(long)m * ldc + n] = val;
  }
}

// ---- LayerNorm: one wave per row, 4 rows/block, no LDS/barriers -----------
__global__ __launch_bounds__(256) void ln_k(const float* __restrict__ s,
                                            float* __restrict__ xout,
                                            const float* __restrict__ g,
                                            const float* __restrict__ be) {
  int wv = threadIdx.x >> 6, lane = threadIdx.x & 63;
  int m = blockIdx.x * 4 + wv;
  float4 v = *(const float4*)(s + (long)m * D_ + lane * 4);
  float sum = v.x + v.y + v.z + v.w;
  float ss = v.x * v.x + v.y * v.y + v.z * v.z + v.w * v.w;
#pragma unroll
  for (int mk = 1; mk < 64; mk <<= 1) {
    sum += __shfl_xor(sum, mk);
    ss += __shfl_xor(ss, mk);
  }
  float mean = sum * (1.0f / D_);
  float inv = rsqrtf(ss * (1.0f / D_) - mean * mean + EPS_);
  float4 g4 = *(const float4*)(g + lane * 4);
  float4 b4 = *(const float4*)(be + lane * 4);
  float4 o;
  o.x = (v.x - mean) * inv * g4.x + b4.x;
  o.y = (v.y - mean) * inv * g4.y + b4.y;
  o.z = (v.z - mean) * inv * g4.z + b4.z;
  o.w = (v.w - mean) * inv * g4.w + b4.w;
  *(float4*)(xout + (long)m * D_ + lane * 4) = o;
}

// ---- causal attention, (h, b, q-half) per block ----------------------------
__global__ __launch_bounds__(256) void attn_k(const float* __restrict__ qkv,
                                              float* __restrict__ ctx) {
  __shared__ float q[20][HD_ + 1];
  __shared__ float k[T_][HD_ + 1];
  __shared__ float v[T_][HD_ + 1];
  __shared__ float s[20][T_ + 1];
  int h = blockIdx.x, b = blockIdx.y, zq = blockIdx.z;
  int r0 = zq * 20;
  int tid = threadIdx.x;
  for (int idx = tid; idx < T_ * HD_; idx += 256) {
    int t = idx >> 6, d = idx & 63;
    long base = (long)(b * T_ + t) * (3 * D_) + h * HD_ + d;
    k[t][d] = qkv[base + D_];
    v[t][d] = qkv[base + 2 * D_];
    if (t < 20) q[t][d] = qkv[(long)(b * T_ + r0 + t) * (3 * D_) + h * HD_ + d];
  }
  __syncthreads();
  for (int idx = tid; idx < 20 * T_; idx += 256) {
    int i = idx / T_, j = idx - i * T_;
    if (j <= r0 + i) {
      float acc = 0.f;
#pragma unroll
      for (int d = 0; d < HD_; ++d) acc += q[i][d] * k[j][d];
      s[i][j] = acc * 0.125f;
    }
  }
  __syncthreads();
  if (tid < 20) {
    int i = tid, hi = r0 + i;
    float mx = -1e30f;
    for (int j = 0; j <= hi; ++j) mx = fmaxf(mx, s[i][j]);
    float sum = 0.f;
    for (int j = 0; j <= hi; ++j) {
      float e = __expf(s[i][j] - mx);
      s[i][j] = e;
      sum += e;
    }
    float inv = 1.0f / sum;
    for (int j = 0; j <= hi; ++j) s[i][j] *= inv;
  }
  __syncthreads();
  for (int idx = tid; idx < 20 * HD_; idx += 256) {
    int i = idx >> 6, d = idx & 63;
    int hi = r0 + i;
    float acc = 0.f;
    for (int j = 0; j <= hi; ++j) acc += s[i][j] * v[j][d];
    ctx[(long)(b * T_ + hi) * D_ + h * HD_ + d] = acc;
  }
}

// ---- fused pproj/cproj/weff, 64x64 tiles; grid (4, 128+20+20) -------------
__global__ __launch_bounds__(256) void fuse3_k(
    const bf16* __restrict__ patb, const float* __restrict__ xbuf,
    const float* __restrict__ cls_w, const bf16* __restrict__ fusb,
    const bf16* __restrict__ w2Tb, const float* __restrict__ fus_b1,
    const int* __restrict__ tokens, float* __restrict__ pprojT,
    float* __restrict__ cw) {
  __shared__ bf16 As[64 * 72];
  __shared__ bf16 Ws[64 * 72];
  const int tid = threadIdx.x;
  const int lane = tid & 63;
  const int wv = tid >> 6;
  const int col = lane & 15, quad = lane >> 4;
  const int bn = blockIdx.x * 64;
  const int y = blockIdx.y;
  int job, bm;
  if (y < 128) { job = 0; bm = y * 64; }
  else if (y < 148) { job = 1; bm = (y - 128) * 64; }
  else { job = 2; bm = (y - 148) * 64; }
  const int K = (job == 0) ? DINO_ : D_;

  f32x4 acc[4];
#pragma unroll
  for (int i = 0; i < 4; ++i) acc[i] = (f32x4){0.f, 0.f, 0.f, 0.f};
  bf16x8 z8 = {};

  for (int kk = 0; kk < K; kk += 64) {
#pragma unroll
    for (int it = 0; it < 2; ++it) {
      int c = tid + it * 256;
      int row = c >> 3, kc = (c & 7) * 8;
      int gm = bm + row;
      bf16x8 av;
      const bf16* wp;
      if (job == 0) {
        av = *(const bf16x8*)(patb + (long)gm * DINO_ + kk + kc);
        wp = fusb + (long)(bn + row) * 640 + kk + kc;
      } else if (job == 1) {
        int t = gm % T_;
        av = (t == 0) ? z8 : cvt8(xbuf + (long)(gm - 1) * D_ + kk + kc);
        wp = fusb + 384 + (long)(bn + row) * 640 + kk + kc;
      } else {
        av = cvt8(cls_w + (long)tokens[gm] * D_ + kk + kc);
        wp = w2Tb + (long)(bn + row) * D_ + kk + kc;
      }
      *(bf16x8*)&As[row * 72 + kc] = av;
      *(bf16x8*)&Ws[row * 72 + kc] = *(const bf16x8*)wp;
    }
    __syncthreads();
#pragma unroll
    for (int ki = 0; ki < 2; ++ki) {
      bf16x8 bfr = *(const bf16x8*)&Ws[(wv * 16 + col) * 72 + ki * 32 + quad * 8];
#pragma unroll
      for (int i = 0; i < 4; ++i) {
        bf16x8 afr = *(const bf16x8*)&As[(i * 16 + col) * 72 + ki * 32 + quad * 8];
        acc[i] = __builtin_amdgcn_mfma_f32_16x16x32_bf16(afr, bfr, acc[i], 0, 0, 0);
      }
    }
    __syncthreads();
  }
  const int n = bn + wv * 16 + col;
  if (job == 0) {
#pragma unroll
    for (int i = 0; i < 4; ++i)
#pragma unroll
      for (int r = 0; r < 4; ++r) {
        int m = bm + i * 16 + quad * 4 + r;
        int b = m >> 8, p = m & 255;
        pprojT[(long)b * (D_ * P_) + (long)n * P_ + p] = acc[i][r];
      }
  } else if (job == 1) {
    float bv = fus_b1[n];
#pragma unroll
    for (int i = 0; i < 4; ++i)
#pragma unroll
      for (int r = 0; r < 4; ++r) {
        int m = bm + i * 16 + quad * 4 + r;
        cw[(long)m * (2 * D_) + n * 2] = acc[i][r] + bv;
      }
  } else {
#pragma unroll
    for (int i = 0; i < 4; ++i)
#pragma unroll
      for (int r = 0; r < 4; ++r) {
        int m = bm + i * 16 + quad * 4 + r;
        cw[(long)m * (2 * D_) + n * 2 + 1] = acc[i][r];
      }
  }
}

// ---- final: out[b,p,t] = sigmoid(sum_e gelu(pp+cp)*we + beff) -------------
__global__ __launch_bounds__(256) void final_k(const float* __restrict__ pprojT,
                                               const float* __restrict__ cw,
                                               const int* __restrict__ tokens,
                                               const float* __restrict__ cls_w,
                                               const float* __restrict__ cls_b,
                                               const float* __restrict__ fus_b2,
                                               float* __restrict__ out) {
  __shared__ float2 cws[4][D_];
  int tid = threadIdx.x;
  int lane = tid & 63, wv = tid >> 6;
  int p = blockIdx.x * 64 + lane;
  int t = blockIdx.y * 4 + wv;
  int b = blockIdx.z;
  int mbase = b * T_ + blockIdx.y * 4;
  for (int idx = tid; idx < 4 * D_; idx += 256) {
    int tt = idx >> 8, e = idx & 255;
    cws[tt][e] = ((const float2*)cw)[(long)(mbase + tt) * D_ + e];
  }
  __syncthreads();

  int m = b * T_ + t;
  int tok = tokens[m];
  const float* cr = cls_w + (long)tok * D_;
  float bacc = 0.f;
#pragma unroll
  for (int i = 0; i < 4; ++i) bacc += cr[lane + i * 64] * fus_b2[lane + i * 64];
#pragma unroll
  for (int mk = 1; mk < 64; mk <<= 1) bacc += __shfl_xor(bacc, mk);
  float beff = bacc + cls_b[tok];

  const float* ppb = pprojT + (long)b * (D_ * P_);  // [e][p]
  float acc = 0.f;
#pragma unroll 8
  for (int e = 0; e < D_; ++e) {
    float pp = ppb[e * P_ + p];
    float2 c = cws[wv][e];
    float x = pp + c.x;
    float x2 = x * x;
    float u = x * fmaf(-0.1029432f, x2, -2.3022083f);  // -log2e*1.5958*(x+0.044715x^3)
    float ex = __builtin_amdgcn_exp2f(u);
    float r = __builtin_amdgcn_rcpf(1.0f + ex);
    acc = fmaf(x * r, c.y, acc);
  }
  float logit = acc + beff;
  float es = __builtin_amdgcn_exp2f(-1.4426950408889634f * logit);
  out[(long)(b * P_ + p) * T_ + t] = __builtin_amdgcn_rcpf(1.0f + es);
}

extern "C" void kernel_launch(void* const* d_in, const int* in_sizes, int n_in, void* d_out,
                              int out_size, void* d_ws, size_t ws_size, hipStream_t stream) {
  const float* patches = (const float*)d_in[0];
  const int* tokens = (const int*)d_in[1];
  const float* tok_emb = (const float*)d_in[2];
  const float* pos_emb = (const float*)d_in[3];
  const float* qkv_w = (const float*)d_in[4];
  const float* qkv_b = (const float*)d_in[5];
  const float* out_w = (const float*)d_in[6];
  const float* out_b = (const float*)d_in[7];
  const float* ln1_s = (const float*)d_in[8];
  const float* ln1_b = (const float*)d_in[9];
  const float* w1 = (const float*)d_in[10];
  const float* b1 = (const float*)d_in[11];
  const float* w2 = (const float*)d_in[12];
  const float* b2 = (const float*)d_in[13];
  const float* ln2_s = (const float*)d_in[14];
  const float* ln2_b = (const float*)d_in[15];
  const float* fus_w1 = (const float*)d_in[16];
  const float* fus_b1 = (const float*)d_in[17];
  const float* fus_w2 = (const float*)d_in[18];
  const float* fus_b2 = (const float*)d_in[19];
  const float* cls_w = (const float*)d_in[20];
  const float* cls_b = (const float*)d_in[21];
  float* out = (float*)d_out;

  const int MT = B_ * T_;  // 1280
  float* x = (float*)d_ws;                     // 1280*256 (embed / LN outs)
  float* qkvbuf = x + MT * D_;                 // 1280*768
  float* attbuf = qkvbuf + MT * 3 * D_;        // 1280*256
  float* s = attbuf + MT * D_;                 // 1280*256 (residual sums)
  float* pprojT = s + MT * D_;                 // 32*256*256 [b][e][p]
  float* cwbuf = pprojT + (long)B_ * D_ * P_;  // 1280*512 {cproj,weff}
  bf16* wb = (bf16*)(cwbuf + MT * D_ * 2);     // bf16 weight arena
  bf16* w2Tb = wb + WB_TOTAL;                  // 256*256
  bf16* patb = w2Tb + D_ * D_;                 // 32*256*384
  bf16* hb = patb + (long)B_ * P_ * DINO_;     // 1280*1024 bf16

  prep_k<<<MT + 64 + CONV_BLOCKS + PAT_BLOCKS, 256, 0, stream>>>(
      tokens, tok_emb, pos_emb, x, fus_w2, w2Tb, qkv_w, out_w, w1, w2, fus_w1, wb,
      patches, patb);

  for (int l = 0; l < L_; ++l) {
    // qkv = x @ qkv_w^T + qkv_b
    gemm64_k<0, 0, 0><<<dim3(12, 20), 256, 0, stream>>>(
        x, wb + OFF_QKV + (long)l * 3 * D_ * D_, qkv_b + l * 3 * D_, qkvbuf,
        D_, D_, D_, 3 * D_);
    attn_k<<<dim3(H_, B_, 2), 256, 0, stream>>>(qkvbuf, attbuf);
    // s = att @ out_w^T + out_b + x
    gemm_k<0, 1><<<dim3(8, 40), 256, 0, stream>>>(
        attbuf, wb + OFF_OUTW + (long)l * D_ * D_, out_b + l * D_, x, s, D_, D_, D_, D_);
    // x = LN1(s)
    ln_k<<<MT / 4, 256, 0, stream>>>(s, x, ln1_s + l * D_, ln1_b + l * D_);
    // hb = relu(x @ w1^T + b1)  (bf16 out)
    gemm64_k<0, 1, 1><<<dim3(16, 20), 256, 0, stream>>>(
        x, wb + OFF_W1 + (long)l * DFF_ * D_, b1 + l * DFF_, hb, D_, D_, D_, DFF_);
    // s = hb @ w2^T + b2 + x
    gemm_k<1, 1><<<dim3(8, 40), 256, 0, stream>>>(
        hb, wb + OFF_W2 + (long)l * D_ * DFF_, b2 + l * D_, x, s, DFF_, DFF_, DFF_, D_);
    // x = LN2(s)
    ln_k<<<MT / 4, 256, 0, stream>>>(s, x, ln2_s + l * D_, ln2_b + l * D_);
  }

  fuse3_k<<<dim3(4, 168), 256, 0, stream>>>(patb, x, cls_w, wb + OFF_FUS, w2Tb,
                                            fus_b1, tokens, pprojT, cwbuf);

  final_k<<<dim3(4, 10, 32), 256, 0, stream>>>(pprojT, cwbuf, tokens, cls_w, cls_b,
                                               fus_b2, out);
}

// Round 11
// 251.724 us; speedup vs baseline: 1.1318x; 1.0733x over previous
//
#include <hip/hip_runtime.h>
#include <hip/hip_bf16.h>

#define B_ 32
#define T_ 40
#define P_ 256
#define V_ 4096
#define D_ 256
#define DINO_ 384
#define H_ 4
#define L_ 2
#define HD_ 64
#define DFF_ 1024
#define EPS_ 1e-5f

typedef __bf16 bf16;
typedef __bf16 bf16x8 __attribute__((ext_vector_type(8)));
typedef float f32x4 __attribute__((ext_vector_type(4)));

// bf16 weight arena offsets (elements)
#define OFF_QKV 0            // 2 x 768*256
#define OFF_OUTW 393216      // 2 x 256*256
#define OFF_W1 524288        // 2 x 1024*256
#define OFF_W2 1048576       // 2 x 256*1024
#define OFF_FUS 1572864      // 256*640
#define WB_TOTAL 1736704
#define CONV_BLOCKS 848      // WB_TOTAL / 2048
#define PAT_BLOCKS 1536      // 32*256*384 / 2048

__device__ __forceinline__ bf16x8 cvt8(const float* p) {
  float4 f0 = *(const float4*)p;
  float4 f1 = *(const float4*)(p + 4);
  bf16x8 v;
  v[0] = (bf16)f0.x; v[1] = (bf16)f0.y; v[2] = (bf16)f0.z; v[3] = (bf16)f0.w;
  v[4] = (bf16)f1.x; v[5] = (bf16)f1.y; v[6] = (bf16)f1.z; v[7] = (bf16)f1.w;
  return v;
}

// ---- prep: embed | fus_w2 transpose->bf16 | weights->bf16 | patches->bf16 --
__global__ __launch_bounds__(256) void prep_k(
    const int* __restrict__ tokens, const float* __restrict__ tok_emb,
    const float* __restrict__ pos_emb, float* __restrict__ x,
    const float* __restrict__ fus_w2, bf16* __restrict__ w2Tb,
    const float* __restrict__ qkv_w, const float* __restrict__ out_w,
    const float* __restrict__ w1, const float* __restrict__ w2,
    const float* __restrict__ fus_w1, bf16* __restrict__ wb,
    const float* __restrict__ patches, bf16* __restrict__ patb) {
  __shared__ float tile[32][33];
  int bi = blockIdx.x;
  int tid = threadIdx.x;
  if (bi < B_ * T_) {
    int t = bi % T_;
    x[bi * D_ + tid] = tok_emb[tokens[bi] * D_ + tid] + pos_emb[t * D_ + tid];
  } else if (bi < B_ * T_ + 64) {
    int tt = bi - B_ * T_;
    int bx = (tt & 7) * 32, by = (tt >> 3) * 32;
    int tx = tid & 31, ty = tid >> 5;  // 32 x 8
#pragma unroll
    for (int i = 0; i < 32; i += 8) tile[ty + i][tx] = fus_w2[(by + ty + i) * D_ + bx + tx];
    __syncthreads();
#pragma unroll
    for (int i = 0; i < 32; i += 8)
      w2Tb[(bx + ty + i) * D_ + by + tx] = (bf16)tile[tx][ty + i];
  } else if (bi < B_ * T_ + 64 + CONV_BLOCKS) {
    long f = (long)(bi - B_ * T_ - 64) * 2048 + tid * 8;
    const float* src;
    long off;
    if (f < OFF_OUTW)      { src = qkv_w;  off = f - OFF_QKV; }
    else if (f < OFF_W1)   { src = out_w;  off = f - OFF_OUTW; }
    else if (f < OFF_W2)   { src = w1;     off = f - OFF_W1; }
    else if (f < OFF_FUS)  { src = w2;     off = f - OFF_W2; }
    else                   { src = fus_w1; off = f - OFF_FUS; }
    *(bf16x8*)&wb[f] = cvt8(src + off);
  } else {
    long f = (long)(bi - B_ * T_ - 64 - CONV_BLOCKS) * 2048 + tid * 8;
    *(bf16x8*)&patb[f] = cvt8(patches + f);
  }
}

// ---- staged MFMA GEMM: 32x32 tile, 4 waves; W bf16; optional resid/relu ----
template <int ABF16, int OBF16, int RELU, int RESID>
__global__ __launch_bounds__(256) void gemm_k(
    const void* __restrict__ Av, const bf16* __restrict__ W,
    const float* __restrict__ bias, const float* __restrict__ resid,
    void* __restrict__ outv, int K, int lda, int ldw, int ldc) {
  __shared__ bf16 As[32 * 72];
  __shared__ bf16 Ws[32 * 72];
  const int tid = threadIdx.x;
  const int lane = tid & 63;
  const int wv = tid >> 6;
  const int mi = wv & 1, ni = wv >> 1;
  const int col = lane & 15, quad = lane >> 4;
  const int bn = blockIdx.x * 32, bm = blockIdx.y * 32;
  const int srow = tid >> 3, kc = (tid & 7) * 8;
  const float* Af = (const float*)Av;
  const bf16* Ab = (const bf16*)Av;
  const bf16* Wp = W + (long)(bn + srow) * ldw + kc;

  f32x4 acc = {0.f, 0.f, 0.f, 0.f};
  for (int kk = 0; kk < K; kk += 64) {
    if (ABF16)
      *(bf16x8*)&As[srow * 72 + kc] = *(const bf16x8*)(Ab + (long)(bm + srow) * lda + kk + kc);
    else
      *(bf16x8*)&As[srow * 72 + kc] = cvt8(Af + (long)(bm + srow) * lda + kk + kc);
    *(bf16x8*)&Ws[srow * 72 + kc] = *(const bf16x8*)(Wp + kk);
    __syncthreads();
#pragma unroll
    for (int ki = 0; ki < 2; ++ki) {
      bf16x8 afr = *(const bf16x8*)&As[(mi * 16 + col) * 72 + ki * 32 + quad * 8];
      bf16x8 bfr = *(const bf16x8*)&Ws[(ni * 16 + col) * 72 + ki * 32 + quad * 8];
      acc = __builtin_amdgcn_mfma_f32_16x16x32_bf16(afr, bfr, acc, 0, 0, 0);
    }
    __syncthreads();
  }
  const int n = bn + ni * 16 + col;
  float bv = bias ? bias[n] : 0.0f;
#pragma unroll
  for (int r = 0; r < 4; ++r) {
    int m = bm + mi * 16 + quad * 4 + r;
    float val = acc[r] + bv;
    if (RESID) val += resid[(long)m * D_ + n];
    if (RELU) val = fmaxf(val, 0.0f);
    if (OBF16) ((bf16*)outv)[(long)m * ldc + n] = (bf16)val;
    else ((float*)outv)[(long)m * ldc + n] = val;
  }
}

// ---- LayerNorm: one wave per row, 4 rows/block, no LDS/barriers -----------
__global__ __launch_bounds__(256) void ln_k(const float* __restrict__ s,
                                            float* __restrict__ xout,
                                            const float* __restrict__ g,
                                            const float* __restrict__ be) {
  int wv = threadIdx.x >> 6, lane = threadIdx.x & 63;
  int m = blockIdx.x * 4 + wv;
  float4 v = *(const float4*)(s + (long)m * D_ + lane * 4);
  float sum = v.x + v.y + v.z + v.w;
  float ss = v.x * v.x + v.y * v.y + v.z * v.z + v.w * v.w;
#pragma unroll
  for (int mk = 1; mk < 64; mk <<= 1) {
    sum += __shfl_xor(sum, mk);
    ss += __shfl_xor(ss, mk);
  }
  float mean = sum * (1.0f / D_);
  float inv = rsqrtf(ss * (1.0f / D_) - mean * mean + EPS_);
  float4 g4 = *(const float4*)(g + lane * 4);
  float4 b4 = *(const float4*)(be + lane * 4);
  float4 o;
  o.x = (v.x - mean) * inv * g4.x + b4.x;
  o.y = (v.y - mean) * inv * g4.y + b4.y;
  o.z = (v.z - mean) * inv * g4.z + b4.z;
  o.w = (v.w - mean) * inv * g4.w + b4.w;
  *(float4*)(xout + (long)m * D_ + lane * 4) = o;
}

// ---- causal attention, (h, b, q-half) per block ----------------------------
__global__ __launch_bounds__(256) void attn_k(const float* __restrict__ qkv,
                                              float* __restrict__ ctx) {
  __shared__ float q[20][HD_ + 1];
  __shared__ float k[T_][HD_ + 1];
  __shared__ float v[T_][HD_ + 1];
  __shared__ float s[20][T_ + 1];
  int h = blockIdx.x, b = blockIdx.y, zq = blockIdx.z;
  int r0 = zq * 20;
  int tid = threadIdx.x;
  for (int idx = tid; idx < T_ * HD_; idx += 256) {
    int t = idx >> 6, d = idx & 63;
    long base = (long)(b * T_ + t) * (3 * D_) + h * HD_ + d;
    k[t][d] = qkv[base + D_];
    v[t][d] = qkv[base + 2 * D_];
    if (t < 20) q[t][d] = qkv[(long)(b * T_ + r0 + t) * (3 * D_) + h * HD_ + d];
  }
  __syncthreads();
  for (int idx = tid; idx < 20 * T_; idx += 256) {
    int i = idx / T_, j = idx - i * T_;
    if (j <= r0 + i) {
      float acc = 0.f;
#pragma unroll
      for (int d = 0; d < HD_; ++d) acc += q[i][d] * k[j][d];
      s[i][j] = acc * 0.125f;
    }
  }
  __syncthreads();
  if (tid < 20) {
    int i = tid, hi = r0 + i;
    float mx = -1e30f;
    for (int j = 0; j <= hi; ++j) mx = fmaxf(mx, s[i][j]);
    float sum = 0.f;
    for (int j = 0; j <= hi; ++j) {
      float e = __expf(s[i][j] - mx);
      s[i][j] = e;
      sum += e;
    }
    float inv = 1.0f / sum;
    for (int j = 0; j <= hi; ++j) s[i][j] *= inv;
  }
  __syncthreads();
  for (int idx = tid; idx < 20 * HD_; idx += 256) {
    int i = idx >> 6, d = idx & 63;
    int hi = r0 + i;
    float acc = 0.f;
    for (int j = 0; j <= hi; ++j) acc += s[i][j] * v[j][d];
    ctx[(long)(b * T_ + hi) * D_ + h * HD_ + d] = acc;
  }
}

// ---- fused pproj/cproj/weff (one launch, grid y-ranges), 32x32 staged -----
// y<256: pproj as C[e][p] = fus_w1 @ patb[b]^T  -> coalesced pprojT stores
// y<296: cproj (ctx-shift) -> cw even; else weff (gathered cls_w) -> cw odd.
__global__ __launch_bounds__(256) void fuse3_k(
    const bf16* __restrict__ patb, const float* __restrict__ xbuf,
    const float* __restrict__ cls_w, const bf16* __restrict__ fusb,
    const bf16* __restrict__ w2Tb, const float* __restrict__ fus_b1,
    const int* __restrict__ tokens, float* __restrict__ pprojT,
    float* __restrict__ cw) {
  __shared__ bf16 As[32 * 72];
  __shared__ bf16 Ws[32 * 72];
  const int tid = threadIdx.x;
  const int lane = tid & 63;
  const int wv = tid >> 6;
  const int mi = wv & 1, ni = wv >> 1;
  const int col = lane & 15, quad = lane >> 4;
  const int bn = blockIdx.x * 32;
  const int y = blockIdx.y;
  const int srow = tid >> 3, kc = (tid & 7) * 8;

  int job, bm, bb = 0;
  if (y < 256) { job = 0; bb = y >> 3; bm = (y & 7) * 32; }
  else if (y < 296) { job = 1; bm = (y - 256) * 32; }
  else { job = 2; bm = (y - 296) * 32; }
  const int gm = bm + srow;

  int K = D_;
  bool zeroA = false;
  const float* Apf = nullptr;
  const bf16* Apb = nullptr;  // A rows (bf16 direct)
  const bf16* Wp;
  if (job == 0) {
    // A = fus_w1 rows (m=e), W = patb[b] rows (n=p)
    Apb = fusb + (long)gm * 640;
    Wp = patb + ((long)bb * P_ + bn + srow) * DINO_ + kc;
    K = DINO_;
  } else if (job == 1) {
    int t = gm % T_;
    zeroA = (t == 0);
    Apf = xbuf + (long)(zeroA ? gm : gm - 1) * D_;
    Wp = fusb + 384 + (long)(bn + srow) * 640 + kc;
  } else {
    Apf = cls_w + (long)tokens[gm] * D_;
    Wp = w2Tb + (long)(bn + srow) * D_ + kc;
  }

  f32x4 acc = {0.f, 0.f, 0.f, 0.f};
  bf16x8 z8 = {};
  for (int kk = 0; kk < K; kk += 64) {
    bf16x8 av;
    if (job == 0) av = *(const bf16x8*)(Apb + kk + kc);
    else if (zeroA) av = z8;
    else av = cvt8(Apf + kk + kc);
    *(bf16x8*)&As[srow * 72 + kc] = av;
    *(bf16x8*)&Ws[srow * 72 + kc] = *(const bf16x8*)(Wp + kk);
    __syncthreads();
#pragma unroll
    for (int ki = 0; ki < 2; ++ki) {
      bf16x8 afr = *(const bf16x8*)&As[(mi * 16 + col) * 72 + ki * 32 + quad * 8];
      bf16x8 bfr = *(const bf16x8*)&Ws[(ni * 16 + col) * 72 + ki * 32 + quad * 8];
      acc = __builtin_amdgcn_mfma_f32_16x16x32_bf16(afr, bfr, acc, 0, 0, 0);
    }
    __syncthreads();
  }
  const int n = bn + ni * 16 + col;
  if (job == 0) {
    // C[m=e][n=p] -> pprojT[b][e][p], coalesced in n
#pragma unroll
    for (int r4 = 0; r4 < 4; ++r4) {
      int e = bm + mi * 16 + quad * 4 + r4;
      pprojT[(long)bb * (D_ * P_) + (long)e * P_ + n] = acc[r4];
    }
  } else if (job == 1) {
    float bv = fus_b1[n];
#pragma unroll
    for (int r4 = 0; r4 < 4; ++r4) {
      int m = bm + mi * 16 + quad * 4 + r4;
      cw[(long)m * (2 * D_) + n * 2] = acc[r4] + bv;
    }
  } else {
#pragma unroll
    for (int r4 = 0; r4 < 4; ++r4) {
      int m = bm + mi * 16 + quad * 4 + r4;
      cw[(long)m * (2 * D_) + n * 2 + 1] = acc[r4];
    }
  }
}

// ---- final: out[b,p,t] = sigmoid(sum_e gelu(pp+cp)*we + beff) -------------
__global__ __launch_bounds__(256) void final_k(const float* __restrict__ pprojT,
                                               const float* __restrict__ cw,
                                               const int* __restrict__ tokens,
                                               const float* __restrict__ cls_w,
                                               const float* __restrict__ cls_b,
                                               const float* __restrict__ fus_b2,
                                               float* __restrict__ out) {
  __shared__ float2 cws[4][D_];
  int tid = threadIdx.x;
  int lane = tid & 63, wv = tid >> 6;
  int p = blockIdx.x * 64 + lane;
  int t = blockIdx.y * 4 + wv;
  int b = blockIdx.z;
  int mbase = b * T_ + blockIdx.y * 4;
  for (int idx = tid; idx < 4 * D_; idx += 256) {
    int tt = idx >> 8, e = idx & 255;
    cws[tt][e] = ((const float2*)cw)[(long)(mbase + tt) * D_ + e];
  }
  __syncthreads();

  int m = b * T_ + t;
  int tok = tokens[m];
  const float* cr = cls_w + (long)tok * D_;
  float bacc = 0.f;
#pragma unroll
  for (int i = 0; i < 4; ++i) bacc += cr[lane + i * 64] * fus_b2[lane + i * 64];
#pragma unroll
  for (int mk = 1; mk < 64; mk <<= 1) bacc += __shfl_xor(bacc, mk);
  float beff = bacc + cls_b[tok];

  const float* ppb = pprojT + (long)b * (D_ * P_);  // [e][p]
  float acc = 0.f;
#pragma unroll 8
  for (int e = 0; e < D_; ++e) {
    float pp = ppb[e * P_ + p];
    float2 c = cws[wv][e];
    float x = pp + c.x;
    float x2 = x * x;
    float u = x * fmaf(-0.1029432f, x2, -2.3022083f);  // -log2e*1.5958*(x+0.044715x^3)
    float ex = __builtin_amdgcn_exp2f(u);
    float r = __builtin_amdgcn_rcpf(1.0f + ex);
    acc = fmaf(x * r, c.y, acc);
  }
  float logit = acc + beff;
  float es = __builtin_amdgcn_exp2f(-1.4426950408889634f * logit);
  out[(long)(b * P_ + p) * T_ + t] = __builtin_amdgcn_rcpf(1.0f + es);
}

extern "C" void kernel_launch(void* const* d_in, const int* in_sizes, int n_in, void* d_out,
                              int out_size, void* d_ws, size_t ws_size, hipStream_t stream) {
  const float* patches = (const float*)d_in[0];
  const int* tokens = (const int*)d_in[1];
  const float* tok_emb = (const float*)d_in[2];
  const float* pos_emb = (const float*)d_in[3];
  const float* qkv_w = (const float*)d_in[4];
  const float* qkv_b = (const float*)d_in[5];
  const float* out_w = (const float*)d_in[6];
  const float* out_b = (const float*)d_in[7];
  const float* ln1_s = (const float*)d_in[8];
  const float* ln1_b = (const float*)d_in[9];
  const float* w1 = (const float*)d_in[10];
  const float* b1 = (const float*)d_in[11];
  const float* w2 = (const float*)d_in[12];
  const float* b2 = (const float*)d_in[13];
  const float* ln2_s = (const float*)d_in[14];
  const float* ln2_b = (const float*)d_in[15];
  const float* fus_w1 = (const float*)d_in[16];
  const float* fus_b1 = (const float*)d_in[17];
  const float* fus_w2 = (const float*)d_in[18];
  const float* fus_b2 = (const float*)d_in[19];
  const float* cls_w = (const float*)d_in[20];
  const float* cls_b = (const float*)d_in[21];
  float* out = (float*)d_out;

  const int MT = B_ * T_;  // 1280
  float* x = (float*)d_ws;                     // 1280*256 (embed / LN outs)
  float* qkvbuf = x + MT * D_;                 // 1280*768
  float* attbuf = qkvbuf + MT * 3 * D_;        // 1280*256
  float* s = attbuf + MT * D_;                 // 1280*256 (residual sums)
  float* pprojT = s + MT * D_;                 // 32*256*256 [b][e][p]
  float* cwbuf = pprojT + (long)B_ * D_ * P_;  // 1280*512 {cproj,weff}
  bf16* wb = (bf16*)(cwbuf + MT * D_ * 2);     // bf16 weight arena
  bf16* w2Tb = wb + WB_TOTAL;                  // 256*256
  bf16* patb = w2Tb + D_ * D_;                 // 32*256*384
  bf16* hb = patb + (long)B_ * P_ * DINO_;     // 1280*1024 bf16

  prep_k<<<MT + 64 + CONV_BLOCKS + PAT_BLOCKS, 256, 0, stream>>>(
      tokens, tok_emb, pos_emb, x, fus_w2, w2Tb, qkv_w, out_w, w1, w2, fus_w1, wb,
      patches, patb);

  for (int l = 0; l < L_; ++l) {
    // qkv = x @ qkv_w^T + qkv_b
    gemm_k<0, 0, 0, 0><<<dim3(24, 40), 256, 0, stream>>>(
        x, wb + OFF_QKV + (long)l * 3 * D_ * D_, qkv_b + l * 3 * D_, nullptr, qkvbuf,
        D_, D_, D_, 3 * D_);
    attn_k<<<dim3(H_, B_, 2), 256, 0, stream>>>(qkvbuf, attbuf);
    // s = att @ out_w^T + out_b + x
    gemm_k<0, 0, 0, 1><<<dim3(8, 40), 256, 0, stream>>>(
        attbuf, wb + OFF_OUTW + (long)l * D_ * D_, out_b + l * D_, x, s, D_, D_, D_, D_);
    // x = LN1(s)
    ln_k<<<MT / 4, 256, 0, stream>>>(s, x, ln1_s + l * D_, ln1_b + l * D_);
    // hb = relu(x @ w1^T + b1)  (bf16 out)
    gemm_k<0, 1, 1, 0><<<dim3(32, 40), 256, 0, stream>>>(
        x, wb + OFF_W1 + (long)l * DFF_ * D_, b1 + l * DFF_, nullptr, hb, D_, D_, D_, DFF_);
    // s = hb @ w2^T + b2 + x
    gemm_k<1, 0, 0, 1><<<dim3(8, 40), 256, 0, stream>>>(
        hb, wb + OFF_W2 + (long)l * D_ * DFF_, b2 + l * D_, x, s, DFF_, DFF_, DFF_, D_);
    // x = LN2(s)
    ln_k<<<MT / 4, 256, 0, stream>>>(s, x, ln2_s + l * D_, ln2_b + l * D_);
  }

  fuse3_k<<<dim3(8, 336), 256, 0, stream>>>(patb, x, cls_w, wb + OFF_FUS, w2Tb,
                                            fus_b1, tokens, pprojT, cwbuf);

  final_k<<<dim3(4, 10, 32), 256, 0, stream>>>(pprojT, cwbuf, tokens, cls_w, cls_b,
                                               fus_b2, out);
}

// Round 12
// 244.398 us; speedup vs baseline: 1.1657x; 1.0300x over previous
//
#include <hip/hip_runtime.h>
#include <hip/hip_bf16.h>

#define B_ 32
#define T_ 40
#define P_ 256
#define V_ 4096
#define D_ 256
#define DINO_ 384
#define H_ 4
#define L_ 2
#define HD_ 64
#define DFF_ 1024
#define EPS_ 1e-5f

typedef __bf16 bf16;
typedef __bf16 bf16x8 __attribute__((ext_vector_type(8)));
typedef float f32x4 __attribute__((ext_vector_type(4)));

// bf16 weight arena offsets (elements)
#define OFF_QKV 0            // 2 x 768*256
#define OFF_OUTW 393216      // 2 x 256*256
#define OFF_W1 524288        // 2 x 1024*256
#define OFF_W2 1048576       // 2 x 256*1024
#define OFF_FUS 1572864      // 256*640
#define WB_TOTAL 1736704
#define CONV_BLOCKS 848      // WB_TOTAL / 2048
#define PAT_BLOCKS 1536      // 32*256*384 / 2048

__device__ __forceinline__ bf16x8 cvt8(const float* p) {
  float4 f0 = *(const float4*)p;
  float4 f1 = *(const float4*)(p + 4);
  bf16x8 v;
  v[0] = (bf16)f0.x; v[1] = (bf16)f0.y; v[2] = (bf16)f0.z; v[3] = (bf16)f0.w;
  v[4] = (bf16)f1.x; v[5] = (bf16)f1.y; v[6] = (bf16)f1.z; v[7] = (bf16)f1.w;
  return v;
}

// ---- prep: embed | fus_w2 transpose->bf16 | weights->bf16 | patches->bf16 --
__global__ __launch_bounds__(256) void prep_k(
    const int* __restrict__ tokens, const float* __restrict__ tok_emb,
    const float* __restrict__ pos_emb, float* __restrict__ x,
    const float* __restrict__ fus_w2, bf16* __restrict__ w2Tb,
    const float* __restrict__ qkv_w, const float* __restrict__ out_w,
    const float* __restrict__ w1, const float* __restrict__ w2,
    const float* __restrict__ fus_w1, bf16* __restrict__ wb,
    const float* __restrict__ patches, bf16* __restrict__ patb) {
  __shared__ float tile[32][33];
  int bi = blockIdx.x;
  int tid = threadIdx.x;
  if (bi < B_ * T_) {
    int t = bi % T_;
    x[bi * D_ + tid] = tok_emb[tokens[bi] * D_ + tid] + pos_emb[t * D_ + tid];
  } else if (bi < B_ * T_ + 64) {
    int tt = bi - B_ * T_;
    int bx = (tt & 7) * 32, by = (tt >> 3) * 32;
    int tx = tid & 31, ty = tid >> 5;  // 32 x 8
#pragma unroll
    for (int i = 0; i < 32; i += 8) tile[ty + i][tx] = fus_w2[(by + ty + i) * D_ + bx + tx];
    __syncthreads();
#pragma unroll
    for (int i = 0; i < 32; i += 8)
      w2Tb[(bx + ty + i) * D_ + by + tx] = (bf16)tile[tx][ty + i];
  } else if (bi < B_ * T_ + 64 + CONV_BLOCKS) {
    long f = (long)(bi - B_ * T_ - 64) * 2048 + tid * 8;
    const float* src;
    long off;
    if (f < OFF_OUTW)      { src = qkv_w;  off = f - OFF_QKV; }
    else if (f < OFF_W1)   { src = out_w;  off = f - OFF_OUTW; }
    else if (f < OFF_W2)   { src = w1;     off = f - OFF_W1; }
    else if (f < OFF_FUS)  { src = w2;     off = f - OFF_W2; }
    else                   { src = fus_w1; off = f - OFF_FUS; }
    *(bf16x8*)&wb[f] = cvt8(src + off);
  } else {
    long f = (long)(bi - B_ * T_ - 64 - CONV_BLOCKS) * 2048 + tid * 8;
    *(bf16x8*)&patb[f] = cvt8(patches + f);
  }
}

// ---- staged MFMA GEMM: 32x32 tile, 4 waves; W bf16; optional resid/relu ----
template <int ABF16, int OBF16, int RELU, int RESID>
__global__ __launch_bounds__(256) void gemm_k(
    const void* __restrict__ Av, const bf16* __restrict__ W,
    const float* __restrict__ bias, const float* __restrict__ resid,
    void* __restrict__ outv, int K, int lda, int ldw, int ldc) {
  __shared__ bf16 As[32 * 72];
  __shared__ bf16 Ws[32 * 72];
  const int tid = threadIdx.x;
  const int lane = tid & 63;
  const int wv = tid >> 6;
  const int mi = wv & 1, ni = wv >> 1;
  const int col = lane & 15, quad = lane >> 4;
  const int bn = blockIdx.x * 32, bm = blockIdx.y * 32;
  const int srow = tid >> 3, kc = (tid & 7) * 8;
  const float* Af = (const float*)Av;
  const bf16* Ab = (const bf16*)Av;
  const bf16* Wp = W + (long)(bn + srow) * ldw + kc;

  f32x4 acc = {0.f, 0.f, 0.f, 0.f};
  for (int kk = 0; kk < K; kk += 64) {
    if (ABF16)
      *(bf16x8*)&As[srow * 72 + kc] = *(const bf16x8*)(Ab + (long)(bm + srow) * lda + kk + kc);
    else
      *(bf16x8*)&As[srow * 72 + kc] = cvt8(Af + (long)(bm + srow) * lda + kk + kc);
    *(bf16x8*)&Ws[srow * 72 + kc] = *(const bf16x8*)(Wp + kk);
    __syncthreads();
#pragma unroll
    for (int ki = 0; ki < 2; ++ki) {
      bf16x8 afr = *(const bf16x8*)&As[(mi * 16 + col) * 72 + ki * 32 + quad * 8];
      bf16x8 bfr = *(const bf16x8*)&Ws[(ni * 16 + col) * 72 + ki * 32 + quad * 8];
      acc = __builtin_amdgcn_mfma_f32_16x16x32_bf16(afr, bfr, acc, 0, 0, 0);
    }
    __syncthreads();
  }
  const int n = bn + ni * 16 + col;
  float bv = bias ? bias[n] : 0.0f;
#pragma unroll
  for (int r = 0; r < 4; ++r) {
    int m = bm + mi * 16 + quad * 4 + r;
    float val = acc[r] + bv;
    if (RESID) val += resid[(long)m * D_ + n];
    if (RELU) val = fmaxf(val, 0.0f);
    if (OBF16) ((bf16*)outv)[(long)m * ldc + n] = (bf16)val;
    else ((float*)outv)[(long)m * ldc + n] = val;
  }
}

// ---- LayerNorm: one wave per row, 4 rows/block, no LDS/barriers -----------
__global__ __launch_bounds__(256) void ln_k(const float* __restrict__ s,
                                            float* __restrict__ xout,
                                            const float* __restrict__ g,
                                            const float* __restrict__ be) {
  int wv = threadIdx.x >> 6, lane = threadIdx.x & 63;
  int m = blockIdx.x * 4 + wv;
  float4 v = *(const float4*)(s + (long)m * D_ + lane * 4);
  float sum = v.x + v.y + v.z + v.w;
  float ss = v.x * v.x + v.y * v.y + v.z * v.z + v.w * v.w;
#pragma unroll
  for (int mk = 1; mk < 64; mk <<= 1) {
    sum += __shfl_xor(sum, mk);
    ss += __shfl_xor(ss, mk);
  }
  float mean = sum * (1.0f / D_);
  float inv = rsqrtf(ss * (1.0f / D_) - mean * mean + EPS_);
  float4 g4 = *(const float4*)(g + lane * 4);
  float4 b4 = *(const float4*)(be + lane * 4);
  float4 o;
  o.x = (v.x - mean) * inv * g4.x + b4.x;
  o.y = (v.y - mean) * inv * g4.y + b4.y;
  o.z = (v.z - mean) * inv * g4.z + b4.z;
  o.w = (v.w - mean) * inv * g4.w + b4.w;
  *(float4*)(xout + (long)m * D_ + lane * 4) = o;
}

// ---- causal attention, (h, b, q-half) per block ----------------------------
__global__ __launch_bounds__(256) void attn_k(const float* __restrict__ qkv,
                                              float* __restrict__ ctx) {
  __shared__ float q[20][HD_ + 1];
  __shared__ float k[T_][HD_ + 1];
  __shared__ float v[T_][HD_ + 1];
  __shared__ float s[20][T_ + 1];
  int h = blockIdx.x, b = blockIdx.y, zq = blockIdx.z;
  int r0 = zq * 20;
  int tid = threadIdx.x;
  int lane = tid & 63, wv = tid >> 6;
  for (int idx = tid; idx < T_ * HD_; idx += 256) {
    int t = idx >> 6, d = idx & 63;
    long base = (long)(b * T_ + t) * (3 * D_) + h * HD_ + d;
    k[t][d] = qkv[base + D_];
    v[t][d] = qkv[base + 2 * D_];
    if (t < 20) q[t][d] = qkv[(long)(b * T_ + r0 + t) * (3 * D_) + h * HD_ + d];
  }
  __syncthreads();
  for (int idx = tid; idx < 20 * T_; idx += 256) {
    int i = idx / T_, j = idx - i * T_;
    if (j <= r0 + i) {
      float acc = 0.f;
#pragma unroll
      for (int d = 0; d < HD_; ++d) acc += q[i][d] * k[j][d];
      s[i][j] = acc * 0.125f;
    }
  }
  __syncthreads();
  // wave-parallel softmax: one wave per row (lanes = j)
  for (int rr = wv; rr < 20; rr += 4) {
    int hi = r0 + rr;
    float val = (lane <= hi) ? s[rr][lane] : -1e30f;
    float mx = val;
#pragma unroll
    for (int mk = 1; mk < 64; mk <<= 1) mx = fmaxf(mx, __shfl_xor(mx, mk));
    float e = (lane <= hi)
                  ? __builtin_amdgcn_exp2f((val - mx) * 1.4426950408889634f)
                  : 0.f;
    float sum = e;
#pragma unroll
    for (int mk = 1; mk < 64; mk <<= 1) sum += __shfl_xor(sum, mk);
    float inv = __builtin_amdgcn_rcpf(sum);
    if (lane < T_) s[rr][lane] = e * inv;
  }
  __syncthreads();
  for (int idx = tid; idx < 20 * HD_; idx += 256) {
    int i = idx >> 6, d = idx & 63;
    int hi = r0 + i;
    float acc = 0.f;
    for (int j = 0; j <= hi; ++j) acc += s[i][j] * v[j][d];
    ctx[(long)(b * T_ + hi) * D_ + h * HD_ + d] = acc;
  }
}

// ---- fused pproj/cproj/weff (one launch, grid y-ranges), 32x32 staged -----
// y<256: pproj as C[e][p] = fus_w1 @ patb[b]^T  -> coalesced pprojT stores
// y<296: cproj with shift+LN2(l=1) folded into A-staging -> cw even
// else:  weff (gathered cls_w) -> cw odd.
__global__ __launch_bounds__(256) void fuse3_k(
    const bf16* __restrict__ patb, const float* __restrict__ sbuf,
    const float* __restrict__ lng, const float* __restrict__ lnb,
    const float* __restrict__ cls_w, const bf16* __restrict__ fusb,
    const bf16* __restrict__ w2Tb, const float* __restrict__ fus_b1,
    const int* __restrict__ tokens, float* __restrict__ pprojT,
    float* __restrict__ cw) {
  __shared__ bf16 As[32 * 264];
  __shared__ bf16 Ws[32 * 72];
  const int tid = threadIdx.x;
  const int lane = tid & 63;
  const int wv = tid >> 6;
  const int mi = wv & 1, ni = wv >> 1;
  const int col = lane & 15, quad = lane >> 4;
  const int bn = blockIdx.x * 32;
  const int y = blockIdx.y;
  const int srow = tid >> 3, kc = (tid & 7) * 8;

  int job, bm, bb = 0;
  if (y < 256) { job = 0; bb = y >> 3; bm = (y & 7) * 32; }
  else if (y < 296) { job = 1; bm = (y - 256) * 32; }
  else { job = 2; bm = (y - 296) * 32; }
  const int gm = bm + srow;

  f32x4 acc = {0.f, 0.f, 0.f, 0.f};
  bf16x8 z8 = {};

  if (job == 1) {
    // A = shift(LN(sbuf)) rows, full K=256 panel (ld 264)
    const int r = srow, cg = (tid & 7) * 32;
    const int t = gm % T_;
    if (t == 0) {
#pragma unroll
      for (int i = 0; i < 4; ++i) *(bf16x8*)&As[r * 264 + cg + i * 8] = z8;
    } else {
      const float* sp = sbuf + (long)(gm - 1) * D_ + cg;
      float v[32];
      float sum = 0.f, ss = 0.f;
#pragma unroll
      for (int i = 0; i < 8; ++i) {
        float4 f = *(const float4*)(sp + i * 4);
        v[i*4] = f.x; v[i*4+1] = f.y; v[i*4+2] = f.z; v[i*4+3] = f.w;
        sum += f.x + f.y + f.z + f.w;
        ss += f.x*f.x + f.y*f.y + f.z*f.z + f.w*f.w;
      }
#pragma unroll
      for (int mk = 1; mk < 8; mk <<= 1) {
        sum += __shfl_xor(sum, mk);
        ss += __shfl_xor(ss, mk);
      }
      float mean = sum * (1.0f / D_);
      float inv = rsqrtf(ss * (1.0f / D_) - mean * mean + EPS_);
#pragma unroll
      for (int i = 0; i < 8; ++i) {
        float4 g4 = *(const float4*)(lng + cg + i * 4);
        float4 b4 = *(const float4*)(lnb + cg + i * 4);
        As[r*264 + cg + i*4]     = (bf16)((v[i*4]   - mean) * inv * g4.x + b4.x);
        As[r*264 + cg + i*4 + 1] = (bf16)((v[i*4+1] - mean) * inv * g4.y + b4.y);
        As[r*264 + cg + i*4 + 2] = (bf16)((v[i*4+2] - mean) * inv * g4.z + b4.z);
        As[r*264 + cg + i*4 + 3] = (bf16)((v[i*4+3] - mean) * inv * g4.w + b4.w);
      }
    }
    __syncthreads();
    const bf16* Wp = fusb + 384 + (long)(bn + srow) * 640 + kc;
    for (int kk = 0; kk < 256; kk += 64) {
      *(bf16x8*)&Ws[srow * 72 + kc] = *(const bf16x8*)(Wp + kk);
      __syncthreads();
#pragma unroll
      for (int ki = 0; ki < 2; ++ki) {
        bf16x8 afr = *(const bf16x8*)&As[(mi*16 + col) * 264 + kk + ki*32 + quad*8];
        bf16x8 bfr = *(const bf16x8*)&Ws[(ni*16 + col) * 72 + ki*32 + quad*8];
        acc = __builtin_amdgcn_mfma_f32_16x16x32_bf16(afr, bfr, acc, 0, 0, 0);
      }
      __syncthreads();
    }
  } else {
    const bf16* Apb;
    const bf16* Wp;
    int K;
    bool gathF = false;
    const float* Apf = nullptr;
    if (job == 0) {
      Apb = fusb + (long)gm * 640;
      Wp = patb + ((long)bb * P_ + bn + srow) * DINO_ + kc;
      K = DINO_;
    } else {
      gathF = true;
      Apf = cls_w + (long)tokens[gm] * D_;
      Wp = w2Tb + (long)(bn + srow) * D_ + kc;
      K = D_;
      Apb = nullptr;
    }
    for (int kk = 0; kk < K; kk += 64) {
      bf16x8 av;
      if (gathF) av = cvt8(Apf + kk + kc);
      else av = *(const bf16x8*)(Apb + kk + kc);
      *(bf16x8*)&As[srow * 72 + kc] = av;
      *(bf16x8*)&Ws[srow * 72 + kc] = *(const bf16x8*)(Wp + kk);
      __syncthreads();
#pragma unroll
      for (int ki = 0; ki < 2; ++ki) {
        bf16x8 afr = *(const bf16x8*)&As[(mi * 16 + col) * 72 + ki * 32 + quad * 8];
        bf16x8 bfr = *(const bf16x8*)&Ws[(ni * 16 + col) * 72 + ki * 32 + quad * 8];
        acc = __builtin_amdgcn_mfma_f32_16x16x32_bf16(afr, bfr, acc, 0, 0, 0);
      }
      __syncthreads();
    }
  }

  const int n = bn + ni * 16 + col;
  if (job == 0) {
#pragma unroll
    for (int r4 = 0; r4 < 4; ++r4) {
      int e = bm + mi * 16 + quad * 4 + r4;
      pprojT[(long)bb * (D_ * P_) + (long)e * P_ + n] = acc[r4];
    }
  } else if (job == 1) {
    float bv = fus_b1[n];
#pragma unroll
    for (int r4 = 0; r4 < 4; ++r4) {
      int m = bm + mi * 16 + quad * 4 + r4;
      cw[(long)m * (2 * D_) + n * 2] = acc[r4] + bv;
    }
  } else {
#pragma unroll
    for (int r4 = 0; r4 < 4; ++r4) {
      int m = bm + mi * 16 + quad * 4 + r4;
      cw[(long)m * (2 * D_) + n * 2 + 1] = acc[r4];
    }
  }
}

// ---- final: out[b,p,t] = sigmoid(sum_e gelu(pp+cp)*we + beff) -------------
// gelu(x) ~= x * sigmoid(1.702 x)  (error <0.005 for |x|<1.5; x sigma~0.5)
__global__ __launch_bounds__(256) void final_k(const float* __restrict__ pprojT,
                                               const float* __restrict__ cw,
                                               const int* __restrict__ tokens,
                                               const float* __restrict__ cls_w,
                                               const float* __restrict__ cls_b,
                                               const float* __restrict__ fus_b2,
                                               float* __restrict__ out) {
  __shared__ float2 cws[4][D_];
  int tid = threadIdx.x;
  int lane = tid & 63, wv = tid >> 6;
  int p = blockIdx.x * 64 + lane;
  int t = blockIdx.y * 4 + wv;
  int b = blockIdx.z;
  int mbase = b * T_ + blockIdx.y * 4;
  for (int idx = tid; idx < 4 * D_; idx += 256) {
    int tt = idx >> 8, e = idx & 255;
    cws[tt][e] = ((const float2*)cw)[(long)(mbase + tt) * D_ + e];
  }
  __syncthreads();

  int m = b * T_ + t;
  int tok = tokens[m];
  const float* cr = cls_w + (long)tok * D_;
  float bacc = 0.f;
#pragma unroll
  for (int i = 0; i < 4; ++i) bacc += cr[lane + i * 64] * fus_b2[lane + i * 64];
#pragma unroll
  for (int mk = 1; mk < 64; mk <<= 1) bacc += __shfl_xor(bacc, mk);
  float beff = bacc + cls_b[tok];

  const float* ppb = pprojT + (long)b * (D_ * P_);  // [e][p]
  float acc = 0.f;
#pragma unroll 8
  for (int e = 0; e < D_; ++e) {
    float pp = ppb[e * P_ + p];
    float2 c = cws[wv][e];
    float x = pp + c.x;
    float ex = __builtin_amdgcn_exp2f(-2.4554248f * x);  // -1.702*log2e
    float r = __builtin_amdgcn_rcpf(1.0f + ex);
    acc = fmaf(x * r, c.y, acc);
  }
  float logit = acc + beff;
  float es = __builtin_amdgcn_exp2f(-1.4426950408889634f * logit);
  out[(long)(b * P_ + p) * T_ + t] = __builtin_amdgcn_rcpf(1.0f + es);
}

extern "C" void kernel_launch(void* const* d_in, const int* in_sizes, int n_in, void* d_out,
                              int out_size, void* d_ws, size_t ws_size, hipStream_t stream) {
  const float* patches = (const float*)d_in[0];
  const int* tokens = (const int*)d_in[1];
  const float* tok_emb = (const float*)d_in[2];
  const float* pos_emb = (const float*)d_in[3];
  const float* qkv_w = (const float*)d_in[4];
  const float* qkv_b = (const float*)d_in[5];
  const float* out_w = (const float*)d_in[6];
  const float* out_b = (const float*)d_in[7];
  const float* ln1_s = (const float*)d_in[8];
  const float* ln1_b = (const float*)d_in[9];
  const float* w1 = (const float*)d_in[10];
  const float* b1 = (const float*)d_in[11];
  const float* w2 = (const float*)d_in[12];
  const float* b2 = (const float*)d_in[13];
  const float* ln2_s = (const float*)d_in[14];
  const float* ln2_b = (const float*)d_in[15];
  const float* fus_w1 = (const float*)d_in[16];
  const float* fus_b1 = (const float*)d_in[17];
  const float* fus_w2 = (const float*)d_in[18];
  const float* fus_b2 = (const float*)d_in[19];
  const float* cls_w = (const float*)d_in[20];
  const float* cls_b = (const float*)d_in[21];
  float* out = (float*)d_out;

  const int MT = B_ * T_;  // 1280
  float* x = (float*)d_ws;                     // 1280*256 (embed / LN outs)
  float* qkvbuf = x + MT * D_;                 // 1280*768
  float* attbuf = qkvbuf + MT * 3 * D_;        // 1280*256
  float* s = attbuf + MT * D_;                 // 1280*256 (residual sums)
  float* pprojT = s + MT * D_;                 // 32*256*256 [b][e][p]
  float* cwbuf = pprojT + (long)B_ * D_ * P_;  // 1280*512 {cproj,weff}
  bf16* wb = (bf16*)(cwbuf + MT * D_ * 2);     // bf16 weight arena
  bf16* w2Tb = wb + WB_TOTAL;                  // 256*256
  bf16* patb = w2Tb + D_ * D_;                 // 32*256*384
  bf16* hb = patb + (long)B_ * P_ * DINO_;     // 1280*1024 bf16

  prep_k<<<MT + 64 + CONV_BLOCKS + PAT_BLOCKS, 256, 0, stream>>>(
      tokens, tok_emb, pos_emb, x, fus_w2, w2Tb, qkv_w, out_w, w1, w2, fus_w1, wb,
      patches, patb);

  for (int l = 0; l < L_; ++l) {
    // qkv = x @ qkv_w^T + qkv_b
    gemm_k<0, 0, 0, 0><<<dim3(24, 40), 256, 0, stream>>>(
        x, wb + OFF_QKV + (long)l * 3 * D_ * D_, qkv_b + l * 3 * D_, nullptr, qkvbuf,
        D_, D_, D_, 3 * D_);
    attn_k<<<dim3(H_, B_, 2), 256, 0, stream>>>(qkvbuf, attbuf);
    // s = att @ out_w^T + out_b + x
    gemm_k<0, 0, 0, 1><<<dim3(8, 40), 256, 0, stream>>>(
        attbuf, wb + OFF_OUTW + (long)l * D_ * D_, out_b + l * D_, x, s, D_, D_, D_, D_);
    // x = LN1(s)
    ln_k<<<MT / 4, 256, 0, stream>>>(s, x, ln1_s + l * D_, ln1_b + l * D_);
    // hb = relu(x @ w1^T + b1)  (bf16 out)
    gemm_k<0, 1, 1, 0><<<dim3(32, 40), 256, 0, stream>>>(
        x, wb + OFF_W1 + (long)l * DFF_ * D_, b1 + l * DFF_, nullptr, hb, D_, D_, D_, DFF_);
    // s = hb @ w2^T + b2 + x
    gemm_k<1, 0, 0, 1><<<dim3(8, 40), 256, 0, stream>>>(
        hb, wb + OFF_W2 + (long)l * D_ * DFF_, b2 + l * D_, x, s, DFF_, DFF_, DFF_, D_);
    // x = LN2(s) — only needed for l=0 (feeds next layer's qkv);
    // l=1's LN2 is folded into fuse3 job-1 staging.
    if (l == 0) ln_k<<<MT / 4, 256, 0, stream>>>(s, x, ln2_s + l * D_, ln2_b + l * D_);
  }

  fuse3_k<<<dim3(8, 336), 256, 0, stream>>>(patb, s, ln2_s + D_, ln2_b + D_, cls_w,
                                            wb + OFF_FUS, w2Tb, fus_b1, tokens,
                                            pprojT, cwbuf);

  final_k<<<dim3(4, 10, 32), 256, 0, stream>>>(pprojT, cwbuf, tokens, cls_w, cls_b,
                                               fus_b2, out);
}